// Round 15
// baseline (382.777 us; speedup 1.0000x reference)
//
#include <hip/hip_runtime.h>

typedef _Float16 v8h __attribute__((ext_vector_type(8)));
typedef float    v4f __attribute__((ext_vector_type(4)));

#define MFMA16(A,B,C) __builtin_amdgcn_mfma_f32_16x16x32_f16((A),(B),(C),0,0,0)

#define RPB 8
#define TT  256
#define HH  64
#define KST 136      // f16 stride per A row: k 0-63 = ha, 64-127 = hb, 8 pad
#define SG  256.0f   // sigmoid LUT index scale (step 1/256), 8192 entries +-16
#define TG  512.0f   // g-gate index scale (tanh(z)=2*sigma(2z)-1)
#define IOFF 4096.5f // LUT index center + 0.5 NN rounding offset

// R15: R12's 2-blocks/CU retried with co-residency actually achievable.
// R14 (215us) is 65% latency-stall at 2 waves/SIMD; R12 failed ONLY on
// LDS fit (2x80,384 = 160,768 vs <160KB effective). Fix: single 8192
// sigma-LUT (g-gate AND c-tanh via 2*sigma(2z)-1, +4 fma/lane-step -
// cheap in stall regime) -> 46.25KB/block, x2 = 92.5KB, fits with margin.
// VGPR ~92 <= 128 -> 4 waves/SIMD. Keeps R14's c-tanh-via-LUT (trans ops
// off the issue port), R12's verified dup-read mapping (l7 A-frag row;
// lane owns rows mr=(q&1)*4+(q>>1)*2,+1 via acc ro=(q>>1)*2,+1), role-
// split waves (w<4 L0: 8 MFMAs, w>=4 L1: 16), setprio, per-tau MFMA->
// gather interleave, 1 barrier/step. MFMA dup tax (pipe ~40%) accepted:
// the 65% stall it fills is bigger.
__global__ __launch_bounds__(512, 2)
void lstm2_kernel(const float* __restrict__ x,     // [4096][256]
                  const float* __restrict__ Wih0,  // [256][1]
                  const float* __restrict__ Whh0,  // [256][64]
                  const float* __restrict__ bih0,
                  const float* __restrict__ bhh0,
                  const float* __restrict__ Wih1,  // [256][64]
                  const float* __restrict__ Whh1,  // [256][64]
                  const float* __restrict__ bih1,
                  const float* __restrict__ bhh1,
                  const float* __restrict__ Wlin,  // [64][64]
                  const float* __restrict__ blin,
                  float* __restrict__ out)         // [4096][64]
{
    __shared__ __align__(16) float xl[TT][RPB];        // 8 KB
    __shared__ __align__(16) _Float16 hs[2][RPB][KST]; // 4.25 KB
    __shared__ float hbF[RPB][HH];                     // 2 KB
    __shared__ float lutS[8192];                       // 32 KB sigma table

    const int tid  = threadIdx.x;
    const int w    = tid >> 6;         // wave 0..7
    const int l15  = tid & 15;
    const int l7   = tid & 7;          // A-frag row (dup: C rows 8-15 -> 0-7)
    const int q    = (tid & 63) >> 4;
    const int row0 = (int)blockIdx.x * RPB;
    const int jj   = (w & 3) * 16 + l15;  // gate column 0..63
    const bool isA = (w < 4);          // wave-uniform: layer0 vs layer1
    const int  ro  = (q >> 1) * 2;            // acc reg base for my rows
    const int  mr  = (q & 1) * 4 + ro;        // my rows: mr, mr+1
    const int  xrb = (q & 1) * 4;             // x rows for acc init

    for (int idx = tid; idx < RPB * TT; idx += 512) {
        int m = idx >> 8, t = idx & 255;
        xl[t][m] = x[(row0 + m) * TT + t];
    }
    for (int idx = tid; idx < 2 * RPB * KST; idx += 512)
        ((_Float16*)hs)[idx] = (_Float16)0.f;
    for (int i = tid; i < 8192; i += 512)
        lutS[i] = 1.0f / (1.0f + __expf(-(i - 4096) * (1.0f / 256.0f)));

    // sigma via clamped NN lookup; F pre-scaled (sigma: 256z, tanh-arg: 512z)
    auto lutSv = [&](float F) -> float {
        F = __builtin_amdgcn_fmed3f(F, 0.0f, 8191.0f);
        return lutS[(int)F];
    };
    // tanh via the sigma table: tanh(z) = 2*sigma(2z)-1; F = 512z + IOFF
    auto lutTh = [&](float F) -> float {
        return fmaf(2.f, lutSv(F), -1.f);
    };

    // ---- register-stationary weights (only MY layer's), LUT index space ----
    float wi0s[4], b0s[4];
    v8h   wh0[4][2];
    v4f   b1v[4];
    v8h   wi1[4][2], wh1[4][2];
    if (isA) {
        #pragma unroll
        for (int tau = 0; tau < 4; tau++) {
            float sc = (tau == 2) ? TG : SG;
            int n = tau * 64 + jj;
            wi0s[tau] = Wih0[n] * sc;
            b0s[tau]  = (bih0[n] + bhh0[n]) * sc + IOFF;
            #pragma unroll
            for (int kk = 0; kk < 2; kk++) {
                int k0 = kk * 32 + q * 8;   // B-frag: B[k0..k0+7][n=lane&15]
                v8h a;
                #pragma unroll
                for (int j = 0; j < 8; j++)
                    a[j] = (_Float16)(Whh0[n * HH + k0 + j] * sc);
                wh0[tau][kk] = a;
            }
        }
    } else {
        #pragma unroll
        for (int tau = 0; tau < 4; tau++) {
            float sc = (tau == 2) ? TG : SG;
            int n = tau * 64 + jj;
            float b1 = (bih1[n] + bhh1[n]) * sc + IOFF;
            b1v[tau] = (v4f){b1, b1, b1, b1};
            #pragma unroll
            for (int kk = 0; kk < 2; kk++) {
                int k0 = kk * 32 + q * 8;
                v8h b, c;
                #pragma unroll
                for (int j = 0; j < 8; j++) {
                    b[j] = (_Float16)(Wih1[n * HH + k0 + j] * sc);
                    c[j] = (_Float16)(Whh1[n * HH + k0 + j] * sc);
                }
                wi1[tau][kk] = b; wh1[tau][kk] = c;
            }
        }
    }

    float cs[2] = {0.f, 0.f};  // c-state of MY layer, rows mr, mr+1
    __syncthreads();

    // ---- prologue t=0: ha(0) from x(0) only (layer-0 waves, 2 rows/lane) ----
    if (isA) {
        #pragma unroll
        for (int i = 0; i < 2; i++) {
            int m = mr + i;
            float xv = xl[0][m];
            float iv = lutSv(fmaf(xv, wi0s[0], b0s[0]));
            float gv = lutTh(fmaf(xv, wi0s[2], b0s[2]));
            float ov = lutSv(fmaf(xv, wi0s[3], b0s[3]));
            cs[i] = iv * gv;
            float th = lutTh(fmaf(cs[i], TG, IOFF));
            hs[0][m][jj] = (_Float16)(ov * th);
        }
    }
    __syncthreads();

    // step k: reads buf[p] {ha(k-1), hb(k-2)}, writes buf[pw] {ha(k), hb(k-1)}
    auto step = [&](int k, int p, int pw, bool last) {
        float sv[4][2];   // [tau][i]
        if (isA) {
            // ---- layer 0: 8 MFMAs, x via rank-1 fmaf init (dup-consistent) ----
            v8h a0 = *(const v8h*)&hs[p][l7][q * 8];           // ha k 0-31
            v8h a1 = *(const v8h*)&hs[p][l7][32 + q * 8];      // ha k 32-63
            int kx = (k < TT) ? k : (TT - 1);                  // k=256: junk
            v4f xv = *(const v4f*)&xl[kx][xrb];                // rows xrb..+3

            // per-tau: MFMA chain (prio-boosted) then its gathers
            #pragma unroll
            for (int tau = 0; tau < 4; tau++) {
                v4f acc;
                #pragma unroll
                for (int r = 0; r < 4; r++)
                    acc[r] = fmaf(xv[r], wi0s[tau], b0s[tau]);
                __builtin_amdgcn_s_setprio(1);
                acc = MFMA16(a0, wh0[tau][0], acc);
                acc = MFMA16(a1, wh0[tau][1], acc);
                __builtin_amdgcn_s_setprio(0);
                if (tau == 2) {
                    #pragma unroll
                    for (int i = 0; i < 2; i++) sv[tau][i] = lutTh(acc[ro + i]);
                } else {
                    #pragma unroll
                    for (int i = 0; i < 2; i++) sv[tau][i] = lutSv(acc[ro + i]);
                }
            }
            // c update + c-tanh gathers (2nd round, hidden by de-phased mates)
            float th[2];
            #pragma unroll
            for (int i = 0; i < 2; i++) {
                cs[i] = fmaf(sv[1][i], cs[i], sv[0][i] * sv[2][i]);
                th[i] = lutTh(fmaf(cs[i], TG, IOFF));
            }
            _Float16* wp = &hs[pw][mr][jj];
            #pragma unroll
            for (int i = 0; i < 2; i++)
                wp[i * KST] = (_Float16)(sv[3][i] * th[i]);
        } else {
            // ---- layer 1: 16 MFMAs over [ha | hb], bias as C operand ----
            v8h a0 = *(const v8h*)&hs[p][l7][q * 8];           // ha k 0-31
            v8h a1 = *(const v8h*)&hs[p][l7][32 + q * 8];      // ha k 32-63
            v8h b0 = *(const v8h*)&hs[p][l7][64 + q * 8];      // hb k 0-31
            v8h b1 = *(const v8h*)&hs[p][l7][96 + q * 8];      // hb k 32-63

            #pragma unroll
            for (int tau = 0; tau < 4; tau++) {
                __builtin_amdgcn_s_setprio(1);
                v4f acc = MFMA16(a0, wi1[tau][0], b1v[tau]);
                acc = MFMA16(a1, wi1[tau][1], acc);
                acc = MFMA16(b0, wh1[tau][0], acc);
                acc = MFMA16(b1, wh1[tau][1], acc);
                __builtin_amdgcn_s_setprio(0);
                if (tau == 2) {
                    #pragma unroll
                    for (int i = 0; i < 2; i++) sv[tau][i] = lutTh(acc[ro + i]);
                } else {
                    #pragma unroll
                    for (int i = 0; i < 2; i++) sv[tau][i] = lutSv(acc[ro + i]);
                }
            }
            float th[2];
            #pragma unroll
            for (int i = 0; i < 2; i++) {
                cs[i] = fmaf(sv[1][i], cs[i], sv[0][i] * sv[2][i]);
                th[i] = lutTh(fmaf(cs[i], TG, IOFF));
            }
            _Float16* wp = &hs[pw][mr][64 + jj];
            #pragma unroll
            for (int i = 0; i < 2; i++) {
                float hv = sv[3][i] * th[i];
                wp[i * KST] = (_Float16)hv;
                if (last) hbF[mr + i][jj] = hv;
            }
        }
        __syncthreads();
    };

    // k = 1..256 (k=256 = layer-1-only epilogue; its ha output junk-but-finite)
    for (int k = 1; k <= TT; k += 2) {
        step(k,     0, 1, false);
        step(k + 1, 1, 0, (k + 1) == TT);
    }

    // ---- out[m][n] = hbF[m][:] . Wlin[n][:] + blin[n] ----
    int m = tid >> 6;             // 0..7
    int n = tid & 63;
    float ao = blin[n];
    #pragma unroll 8
    for (int j = 0; j < HH; j++)
        ao = fmaf(hbF[m][j], Wlin[n * HH + j], ao);
    out[(row0 + m) * HH + n] = ao;
}

extern "C" void kernel_launch(void* const* d_in, const int* in_sizes, int n_in,
                              void* d_out, int out_size, void* d_ws, size_t ws_size,
                              hipStream_t stream) {
    const float* x    = (const float*)d_in[0];
    const float* Wih0 = (const float*)d_in[1];
    const float* Whh0 = (const float*)d_in[2];
    const float* bih0 = (const float*)d_in[3];
    const float* bhh0 = (const float*)d_in[4];
    const float* Wih1 = (const float*)d_in[5];
    const float* Whh1 = (const float*)d_in[6];
    const float* bih1 = (const float*)d_in[7];
    const float* bhh1 = (const float*)d_in[8];
    const float* Wlin = (const float*)d_in[9];
    const float* blin = (const float*)d_in[10];
    // 4096 rows / 8 per block = 512 blocks = 2 de-phased blocks/CU
    // (46.25KB LDS/block -> 92.5KB/CU, co-residency fits with margin)
    lstm2_kernel<<<512, 512, 0, stream>>>(x, Wih0, Whh0, bih0, bhh0,
                                          Wih1, Whh1, bih1, bhh1,
                                          Wlin, blin, (float*)d_out);
}

// Round 16
// 264.547 us; speedup vs baseline: 1.4469x; 1.4469x over previous
//
#include <hip/hip_runtime.h>

typedef _Float16 v8h __attribute__((ext_vector_type(8)));
typedef float    v4f __attribute__((ext_vector_type(4)));

#define MFMA16(A,B,C) __builtin_amdgcn_mfma_f32_16x16x32_f16((A),(B),(C),0,0,0)

#define RPB 16
#define TT  256
#define HH  64
#define KST 136      // f16 stride per A row: k 0-63 = ha, 64-127 = hb, 8 pad
#define SG  256.0f     // sigmoid LUT scale (step 1/256), 16384 entries, z +-32
#define IOFF_S 8192.5f // sigma index center + 0.5 NN rounding
#define TG  512.0f     // tanh LUT scale (step 1/512), 8192 entries, z +-8
#define IOFF_T 4096.5f // tanh index center + 0.5 NN rounding

// R16 = R14 restored (verified best: 215.2us profiled). R15 proved 2
// blocks/CU never co-reside for 512-thread WGs on this part (occupancy
// pinned at one block even with LDS 95KB < 160KB; grid ran as 2 serial
// passes) -> occupancy axis closed twice (R12, R15). R14's stack:
// - 16 real batch rows, layer-split waves (w<4 L0: 8 MFMAs + x rank-1
//   init; w>=4 L1: 16 MFMAs), no MFMA duplication (R6, +19%)
// - all activations via LDS NN LUTs, zero trans ops on the issue port:
//   clamp-free 16K-entry sigma (R13), 8K tanh for g-gate AND c-tanh
//   (R14; gather conflicts measured-free, kappa~0, R6/R7/R8 triplet)
// - per-tau MFMA->gather interleave (R9), s_setprio(1) around MFMA
//   clusters (R11, +12% - role-split L0/L1 SIMD-pair arbitration)
// - 1 barrier/step, double-buffered hs, f16 h-state
// Residual ~65% is the serial recurrence latency chain at the HW-capped
// 2 waves/SIMD - structural floor, not a pipe roofline.
__global__ __launch_bounds__(512, 2)
void lstm2_kernel(const float* __restrict__ x,     // [4096][256]
                  const float* __restrict__ Wih0,  // [256][1]
                  const float* __restrict__ Whh0,  // [256][64]
                  const float* __restrict__ bih0,
                  const float* __restrict__ bhh0,
                  const float* __restrict__ Wih1,  // [256][64]
                  const float* __restrict__ Whh1,  // [256][64]
                  const float* __restrict__ bih1,
                  const float* __restrict__ bhh1,
                  const float* __restrict__ Wlin,  // [64][64]
                  const float* __restrict__ blin,
                  float* __restrict__ out)         // [4096][64]
{
    __shared__ float xl[TT][RPB];                      // 16 KB
    __shared__ __align__(16) _Float16 hs[2][RPB][KST]; // 8.5 KB
    __shared__ float hbF[RPB][HH];                     // 4 KB
    __shared__ float lutS[16384];                      // 64 KB sigma, z +-32
    __shared__ float lutT[8192];                       // 32 KB tanh,  z +-8

    const int tid  = threadIdx.x;
    const int w    = tid >> 6;         // wave 0..7
    const int l15  = tid & 15;         // A-frag row = batch row (no dup)
    const int q    = (tid & 63) >> 4;  // k-group / pointwise row-quad
    const int row0 = (int)blockIdx.x * RPB;
    const int jj   = (w & 3) * 16 + l15;  // gate column 0..63
    const bool isA = (w < 4);          // wave-uniform: layer0 vs layer1
    const int  mr  = q * 4;            // my pointwise row base (0,4,8,12)

    for (int idx = tid; idx < RPB * TT; idx += 512) {
        int m = idx & 15, t = idx >> 4;
        xl[t][m] = x[(row0 + m) * TT + t];
    }
    for (int idx = tid; idx < 2 * RPB * KST; idx += 512)
        ((_Float16*)hs)[idx] = (_Float16)0.f;
    for (int i = tid; i < 16384; i += 512)
        lutS[i] = 1.0f / (1.0f + __expf(-(i - 8192) * (1.0f / 256.0f)));
    for (int i = tid; i < 8192; i += 512) {
        float e = __expf(-(i - 4096) * (1.0f / 256.0f));
        lutT[i] = 2.0f / (1.0f + e) - 1.0f;   // tanh((i-4096)/512)
    }

    // sigma: clamp-free NN lookup; F = 256z + 8192.5, |z| bounded << 32
    auto lutSv = [&](float F) -> float {
        return lutS[(int)F];
    };
    // tanh: clamped NN lookup; F = 512z + 4096.5 (used by g-gate AND c)
    auto lutTv = [&](float F) -> float {
        F = __builtin_amdgcn_fmed3f(F, 0.0f, 8191.0f);
        return lutT[(int)F];
    };

    // ---- register-stationary weights (only MY layer's), LUT index space ----
    float wi0s[4], b0s[4];
    v8h   wh0[4][2];
    v4f   b1v[4];
    v8h   wi1[4][2], wh1[4][2];
    if (isA) {
        #pragma unroll
        for (int tau = 0; tau < 4; tau++) {
            float sc  = (tau == 2) ? TG : SG;
            float off = (tau == 2) ? IOFF_T : IOFF_S;
            int n = tau * 64 + jj;
            wi0s[tau] = Wih0[n] * sc;
            b0s[tau]  = (bih0[n] + bhh0[n]) * sc + off;
            #pragma unroll
            for (int kk = 0; kk < 2; kk++) {
                int k0 = kk * 32 + q * 8;   // B-frag: B[k0..k0+7][n=lane&15]
                v8h a;
                #pragma unroll
                for (int j = 0; j < 8; j++)
                    a[j] = (_Float16)(Whh0[n * HH + k0 + j] * sc);
                wh0[tau][kk] = a;
            }
        }
    } else {
        #pragma unroll
        for (int tau = 0; tau < 4; tau++) {
            float sc  = (tau == 2) ? TG : SG;
            float off = (tau == 2) ? IOFF_T : IOFF_S;
            int n = tau * 64 + jj;
            float b1 = (bih1[n] + bhh1[n]) * sc + off;
            b1v[tau] = (v4f){b1, b1, b1, b1};
            #pragma unroll
            for (int kk = 0; kk < 2; kk++) {
                int k0 = kk * 32 + q * 8;
                v8h b, c;
                #pragma unroll
                for (int j = 0; j < 8; j++) {
                    b[j] = (_Float16)(Wih1[n * HH + k0 + j] * sc);
                    c[j] = (_Float16)(Whh1[n * HH + k0 + j] * sc);
                }
                wi1[tau][kk] = b; wh1[tau][kk] = c;
            }
        }
    }

    float cs[4] = {0.f, 0.f, 0.f, 0.f};  // c-state of MY layer, rows mr..mr+3
    __syncthreads();

    // ---- prologue t=0: ha(0) from x(0) only (layer-0 waves) ----
    if (isA) {
        #pragma unroll
        for (int r = 0; r < 4; r++) {
            int m = mr + r;
            float xv = xl[0][m];
            float iv = lutSv(fmaf(xv, wi0s[0], b0s[0]));
            float gv = lutTv(fmaf(xv, wi0s[2], b0s[2]));
            float ov = lutSv(fmaf(xv, wi0s[3], b0s[3]));
            cs[r] = iv * gv;
            float th = lutTv(fmaf(cs[r], TG, IOFF_T));
            hs[0][m][jj] = (_Float16)(ov * th);
        }
    }
    __syncthreads();

    // step k: reads buf[p] {ha(k-1), hb(k-2)}, writes buf[pw] {ha(k), hb(k-1)}
    auto step = [&](int k, int p, int pw, bool last) {
        float sv[4][4];   // [tau][r]
        if (isA) {
            // ---- layer 0: 8 MFMAs, x via rank-1 fmaf init ----
            v8h a0 = *(const v8h*)&hs[p][l15][q * 8];          // ha k 0-31
            v8h a1 = *(const v8h*)&hs[p][l15][32 + q * 8];     // ha k 32-63
            int kx = (k < TT) ? k : (TT - 1);                  // k=256: junk
            v4f xv = *(const v4f*)&xl[kx][mr];

            // per-tau: MFMA chain (prio-boosted) then its gathers -> gather
            // latency hides under the next tau's MFMA issue
            #pragma unroll
            for (int tau = 0; tau < 4; tau++) {
                v4f acc;
                #pragma unroll
                for (int r = 0; r < 4; r++)
                    acc[r] = fmaf(xv[r], wi0s[tau], b0s[tau]);
                __builtin_amdgcn_s_setprio(1);
                acc = MFMA16(a0, wh0[tau][0], acc);
                acc = MFMA16(a1, wh0[tau][1], acc);
                __builtin_amdgcn_s_setprio(0);
                if (tau == 2) {
                    #pragma unroll
                    for (int r = 0; r < 4; r++) sv[tau][r] = lutTv(acc[r]);
                } else {
                    #pragma unroll
                    for (int r = 0; r < 4; r++) sv[tau][r] = lutSv(acc[r]);
                }
            }
            // c update + c-tanh gathers (2nd round, hidden by SIMD-mate)
            float th[4];
            #pragma unroll
            for (int r = 0; r < 4; r++) {
                cs[r] = fmaf(sv[1][r], cs[r], sv[0][r] * sv[2][r]);
                th[r] = lutTv(fmaf(cs[r], TG, IOFF_T));
            }
            _Float16* wp = &hs[pw][mr][jj];
            #pragma unroll
            for (int r = 0; r < 4; r++)
                wp[r * KST] = (_Float16)(sv[3][r] * th[r]);
        } else {
            // ---- layer 1: 16 MFMAs over [ha | hb], bias as C operand ----
            v8h a0 = *(const v8h*)&hs[p][l15][q * 8];          // ha k 0-31
            v8h a1 = *(const v8h*)&hs[p][l15][32 + q * 8];     // ha k 32-63
            v8h b0 = *(const v8h*)&hs[p][l15][64 + q * 8];     // hb k 0-31
            v8h b1 = *(const v8h*)&hs[p][l15][96 + q * 8];     // hb k 32-63

            #pragma unroll
            for (int tau = 0; tau < 4; tau++) {
                __builtin_amdgcn_s_setprio(1);
                v4f acc = MFMA16(a0, wi1[tau][0], b1v[tau]);
                acc = MFMA16(a1, wi1[tau][1], acc);
                acc = MFMA16(b0, wh1[tau][0], acc);
                acc = MFMA16(b1, wh1[tau][1], acc);
                __builtin_amdgcn_s_setprio(0);
                if (tau == 2) {
                    #pragma unroll
                    for (int r = 0; r < 4; r++) sv[tau][r] = lutTv(acc[r]);
                } else {
                    #pragma unroll
                    for (int r = 0; r < 4; r++) sv[tau][r] = lutSv(acc[r]);
                }
            }
            float th[4];
            #pragma unroll
            for (int r = 0; r < 4; r++) {
                cs[r] = fmaf(sv[1][r], cs[r], sv[0][r] * sv[2][r]);
                th[r] = lutTv(fmaf(cs[r], TG, IOFF_T));
            }
            _Float16* wp = &hs[pw][mr][64 + jj];
            #pragma unroll
            for (int r = 0; r < 4; r++) {
                float hv = sv[3][r] * th[r];
                wp[r * KST] = (_Float16)hv;
                if (last) hbF[mr + r][jj] = hv;
            }
        }
        __syncthreads();
    };

    // k = 1..256 (k=256 = layer-1-only epilogue; its ha output junk-but-finite)
    for (int k = 1; k <= TT; k += 2) {
        step(k,     0, 1, false);
        step(k + 1, 1, 0, (k + 1) == TT);
    }

    // ---- out[m][n] = hbF[m][:] . Wlin[n][:] + blin[n] ----
    int m  = tid >> 5;            // 0..15
    int n0 = (tid & 31) * 2;
    float a0o = blin[n0], a1o = blin[n0 + 1];
    #pragma unroll 8
    for (int j = 0; j < HH; j++) {
        float h = hbF[m][j];
        a0o = fmaf(h, Wlin[(n0 + 0) * HH + j], a0o);
        a1o = fmaf(h, Wlin[(n0 + 1) * HH + j], a1o);
    }
    out[(row0 + m) * HH + n0]     = a0o;
    out[(row0 + m) * HH + n0 + 1] = a1o;
}

extern "C" void kernel_launch(void* const* d_in, const int* in_sizes, int n_in,
                              void* d_out, int out_size, void* d_ws, size_t ws_size,
                              hipStream_t stream) {
    const float* x    = (const float*)d_in[0];
    const float* Wih0 = (const float*)d_in[1];
    const float* Whh0 = (const float*)d_in[2];
    const float* bih0 = (const float*)d_in[3];
    const float* bhh0 = (const float*)d_in[4];
    const float* Wih1 = (const float*)d_in[5];
    const float* Whh1 = (const float*)d_in[6];
    const float* bih1 = (const float*)d_in[7];
    const float* bhh1 = (const float*)d_in[8];
    const float* Wlin = (const float*)d_in[9];
    const float* blin = (const float*)d_in[10];
    // 4096 rows / 16 per block = 256 blocks = 1 block/CU, 8 waves (2/SIMD)
    lstm2_kernel<<<256, 512, 0, stream>>>(x, Wih0, Whh0, bih0, bhh0,
                                          Wih1, Whh1, bih1, bhh1,
                                          Wlin, blin, (float*)d_out);
}